// Round 4
// baseline (209.253 us; speedup 1.0000x reference)
//
#include <hip/hip_runtime.h>
#include <cstdint>
#include <cstddef>

// Problem constants: B=2, N=16384, K=32, F=64, E=16
#define LOGN 14

typedef __bf16 bf16x8 __attribute__((ext_vector_type(8)));
typedef float f32x4 __attribute__((ext_vector_type(4)));

__device__ __forceinline__ unsigned bf16rne(float f) {
  unsigned u = __builtin_bit_cast(unsigned, f);
  return (u + 0x7fffu + ((u >> 16) & 1u)) >> 16;
}

// wt[m][k] = w[l][m][n] / 32, k = l*16 + n  (bf16), 64x1024 = 128KB
__global__ void prep_wt(const float* __restrict__ w, unsigned short* __restrict__ wt) {
  int idx = blockIdx.x * 256 + threadIdx.x;   // 65536 total
  int m = idx >> 10, k = idx & 1023, l = k >> 4, n = k & 15;
  wt[idx] = (unsigned short)bf16rne(w[l * 1024 + m * 16 + n] * 0.03125f);
}

// Gather one node's S column-slice: sv[j] = nodes[nl[j]][lane].
// Row index comes from v_readlane of a pre-loaded nlist vector register —
// NO scalar memory in the path (R3's per-j s_load → lgkmcnt drain killed MLP).
// Address = scalar base (SALU) + lane offset → global_load_dword saddr form.
__device__ __forceinline__ void gather_rl(const float* __restrict__ nbase,
                                          int nlv, int jbase, int lane,
                                          float* __restrict__ sv) {
  #pragma unroll
  for (int j = 0; j < 32; ++j) {
    const int ix = __builtin_amdgcn_readlane(nlv, jbase + j);   // uniform
    sv[j] = nbase[((size_t)(unsigned)ix << 6) + lane];
  }
}

// FMA loop: e from LDS broadcast (uniform-addr ds_read_b128), s from regs.
// Pack G to bf16, store to phase-B A-frag layout with node-XOR swizzle.
__device__ __forceinline__ void compute_node(const uint4* __restrict__ eb,
                                             const float* __restrict__ sv,
                                             int lane, int nd,
                                             uint4* __restrict__ g_lds) {
  const float4* __restrict__ e4 = (const float4*)eb;
  float G[16];
  #pragma unroll
  for (int n = 0; n < 16; ++n) G[n] = 0.f;
  #pragma unroll
  for (int j = 0; j < 32; ++j) {
    float e[16];
    *(float4*)&e[0]  = e4[4 * j + 0];
    *(float4*)&e[4]  = e4[4 * j + 1];
    *(float4*)&e[8]  = e4[4 * j + 2];
    *(float4*)&e[12] = e4[4 * j + 3];
    const float s = sv[j];
    #pragma unroll
    for (int n = 0; n < 16; ++n) G[n] = fmaf(s, e[n], G[n]);
  }
  unsigned pk[8];
  #pragma unroll
  for (int h = 0; h < 8; ++h)
    pk[h] = bf16rne(G[2 * h]) | (bf16rne(G[2 * h + 1]) << 16);
  const int nxw = nd & 7;
  uint4* dst = g_lds + nd * 128;
  dst[lane ^ nxw]        = uint4{pk[0], pk[1], pk[2], pk[3]};   // h=0: n 0..7
  dst[64 + (lane ^ nxw)] = uint4{pk[4], pk[5], pk[6], pk[7]};   // h=1: n 8..15
}

// One workgroup = 256 threads (4 waves) = 16 nodes.
// LDS: 32 KB G + 16 KB per-wave double-buffered edge stage = 48 KB -> 3 blk/CU.
// Phase A per wave (4 nodes, software-pipelined):
//   nlist for all 4 nodes loaded up-front as 2 per-lane vector loads (128
//   consecutive ints), indices extracted via v_readlane; gathers for node p+1
//   overlap the FMA loop of node p (svA/svB reg double-buffer, ~124 VGPR).
//   Edges staged via coalesced global_load_dwordx4 -> LDS broadcast.
// Phase B: wave wid = m-tile; C = 16 nodes x 16 m; 32 K-steps of
//   mfma_f32_16x16x32_bf16, A from LDS, B from wt (L2-resident).
template <bool USE_WT>
__global__ __launch_bounds__(256, 3)
void mp_kernel(const float* __restrict__ nodes, const int* __restrict__ nlist,
               const float* __restrict__ edges, const unsigned short* __restrict__ wt,
               const float* __restrict__ w, float* __restrict__ out) {
  __shared__ uint4 g_lds[16 * 128];     // 32 KB: G (bf16) in phase-B A-frag order
  __shared__ uint4 ebuf[4][2][128];     // 16 KB: per-wave double-buffered edge stage

  const int tid = threadIdx.x;
  const int lane = tid & 63;
  const int wid = __builtin_amdgcn_readfirstlane(tid >> 6);

  // XCD-aware mapping: batch b's nodes slab (4 MB) stays on 4 XCDs' L2.
  const int blk = blockIdx.x;
  const int xcd = blk & 7;
  const int batch = xcd >> 2;
  const int ordinal = ((blk >> 3) << 2) + (xcd & 3);     // [0,1024)
  const int wg0 = (batch << LOGN) + (ordinal << 4);      // flat node base
  const float* __restrict__ nbase = nodes + ((size_t)batch << 20);

  // ---------------- Phase A ----------------
  {
    const int nd0 = wid << 2;
    const size_t g0 = (size_t)wg0 + nd0;
    uint4* eb0 = &ebuf[wid][0][0];
    uint4* eb1 = &ebuf[wid][1][0];

    // nlist rows for this wave's 4 nodes: 128 consecutive ints, 2 vector loads.
    const int* __restrict__ nlp = nlist + (g0 << 5);
    const int nlv0 = nlp[lane];          // nodes 0,1 (j = lane, lane-32)
    const int nlv1 = nlp[64 + lane];     // nodes 2,3

    float svA[32], svB[32];
    uint4 ta0, ta1, tb0, tb1;

    { const uint4* eg = (const uint4*)(edges + ((g0 + 0) << 9));
      ta0 = eg[lane]; ta1 = eg[64 + lane]; }               // eload(0)
    { const uint4* eg = (const uint4*)(edges + ((g0 + 1) << 9));
      tb0 = eg[lane]; tb1 = eg[64 + lane]; }               // eload(1)

    gather_rl(nbase, nlv0, 0,  lane, svA);                 // gather(0)
    gather_rl(nbase, nlv0, 32, lane, svB);                 // gather(1)

    eb0[lane] = ta0; eb0[64 + lane] = ta1;                 // ewrite(0)
    { const uint4* eg = (const uint4*)(edges + ((g0 + 2) << 9));
      ta0 = eg[lane]; ta1 = eg[64 + lane]; }               // eload(2)
    compute_node(eb0, svA, lane, nd0 + 0, g_lds);          // node 0

    eb1[lane] = tb0; eb1[64 + lane] = tb1;                 // ewrite(1)
    { const uint4* eg = (const uint4*)(edges + ((g0 + 3) << 9));
      tb0 = eg[lane]; tb1 = eg[64 + lane]; }               // eload(3)
    gather_rl(nbase, nlv1, 0, lane, svA);                  // gather(2)
    compute_node(eb1, svB, lane, nd0 + 1, g_lds);          // node 1

    eb0[lane] = ta0; eb0[64 + lane] = ta1;                 // ewrite(2)
    gather_rl(nbase, nlv1, 32, lane, svB);                 // gather(3)
    compute_node(eb0, svA, lane, nd0 + 2, g_lds);          // node 2

    eb1[lane] = tb0; eb1[64 + lane] = tb1;                 // ewrite(3)
    compute_node(eb1, svB, lane, nd0 + 3, g_lds);          // node 3
  }

  __syncthreads();

  // ---------------- Phase B: out = G @ wt^T via MFMA ----------------
  const int col = lane & 15;            // A-row (node) AND D-col (m) index
  const int q   = lane >> 4;
  const int mcol = (wid << 4) + col;    // m in [0,64)
  const int nx = col & 7;
  const int cbase = ((q & 1) << 6) + (q >> 1);   // logical chunk: h*64 + l-off
  const int row0 = col << 7;            // node row base (uint4 units)

  f32x4 acc = {0.f, 0.f, 0.f, 0.f};

  if (USE_WT) {
    const unsigned short* bp = wt + ((size_t)mcol << 10) + (q << 3);
    #pragma unroll 8
    for (int s = 0; s < 32; ++s) {
      const int coff = (cbase + (s << 1)) ^ nx;
      bf16x8 a0 = __builtin_bit_cast(bf16x8, g_lds[row0 + coff]);
      bf16x8 bb = *(const bf16x8*)(bp + (s << 5));
      acc = __builtin_amdgcn_mfma_f32_16x16x32_bf16(a0, bb, acc, 0, 0, 0);
    }
  } else {
    #pragma unroll 4
    for (int s = 0; s < 32; ++s) {
      const int coff = (cbase + (s << 1)) ^ nx;
      bf16x8 a0 = __builtin_bit_cast(bf16x8, g_lds[row0 + coff]);
      const int l = (s << 1) + (q >> 1);
      const float* wp = w + l * 1024 + mcol * 16 + ((q & 1) << 3);
      bf16x8 bb;
      #pragma unroll
      for (int jj = 0; jj < 8; ++jj) bb[jj] = (__bf16)(wp[jj] * 0.03125f);
      acc = __builtin_amdgcn_mfma_f32_16x16x32_bf16(a0, bb, acc, 0, 0, 0);
    }
  }

  // D layout: col = lane&15 (m), row = q*4 + r (node-in-tile)
  #pragma unroll
  for (int r = 0; r < 4; ++r)
    out[((size_t)(wg0 + (q << 2) + r) << 6) + mcol] = acc[r];
}

extern "C" void kernel_launch(void* const* d_in, const int* in_sizes, int n_in,
                              void* d_out, int out_size, void* d_ws, size_t ws_size,
                              hipStream_t stream) {
  const float* nodes = (const float*)d_in[0];
  const int*   nlist = (const int*)d_in[1];
  const float* edges = (const float*)d_in[2];
  const float* w     = (const float*)d_in[3];
  float* out = (float*)d_out;

  if (ws_size >= 131072) {
    unsigned short* wt = (unsigned short*)d_ws;
    prep_wt<<<256, 256, 0, stream>>>(w, wt);
    mp_kernel<true><<<2048, 256, 0, stream>>>(nodes, nlist, edges, wt, w, out);
  } else {
    mp_kernel<false><<<2048, 256, 0, stream>>>(nodes, nlist, edges, nullptr, w, out);
  }
}

// Round 5
// 201.752 us; speedup vs baseline: 1.0372x; 1.0372x over previous
//
#include <hip/hip_runtime.h>
#include <cstdint>
#include <cstddef>

// Problem constants: B=2, N=16384, K=32, F=64, E=16
#define LOGN 14

typedef __bf16 bf16x8 __attribute__((ext_vector_type(8)));
typedef float f32x4 __attribute__((ext_vector_type(4)));
typedef unsigned u32;
typedef __attribute__((address_space(1))) u32 GlbU32;
typedef __attribute__((address_space(3))) u32 LdsU32;

// s_waitcnt with vmcnt(n), lgkm/exp unconstrained (gfx9 encoding)
#define WAITVM(n) __builtin_amdgcn_s_waitcnt(0x0F70 | ((n) & 0xF) | (((n) & 0x30) << 10))

__device__ __forceinline__ u32 fbits(float f) { return __builtin_bit_cast(u32, f); }
// pack two f32 -> dword of 2 bf16 (RNE), lo -> low16
__device__ __forceinline__ u32 pkrne(float lo, float hi) {
  u32 a = fbits(lo); a = a + 0x7fffu + ((a >> 16) & 1u);
  u32 b = fbits(hi); b = b + 0x7fffu + ((b >> 16) & 1u);
  return (b & 0xffff0000u) | (a >> 16);
}

// wt[m][k] = w[l][m][n]/32, k = l*16+n (bf16), 64x1024 = 128KB
__global__ void prep_wt(const float* __restrict__ w, unsigned short* __restrict__ wt) {
  int idx = blockIdx.x * 256 + threadIdx.x;
  int m = idx >> 10, k = idx & 1023, l = k >> 4, n = k & 15;
  u32 u = fbits(w[l * 1024 + m * 16 + n] * 0.03125f);
  wt[idx] = (unsigned short)((u + 0x7fffu + ((u >> 16) & 1u)) >> 16);
}

__device__ __forceinline__ bf16x8 mk_bw(const float* wp) {
  float v[8];
  #pragma unroll
  for (int i = 0; i < 8; ++i) v[i] = wp[i] * 0.03125f;
  uint4 pk{pkrne(v[0], v[1]), pkrne(v[2], v[3]), pkrne(v[4], v[5]), pkrne(v[6], v[7])};
  return __builtin_bit_cast(bf16x8, pk);
}

// ============================================================================
// One workgroup = ONE wave = 16 nodes. No barriers anywhere.
// Phase A per node: G^T[n_e][l] = sum_j E[j][n_e] * S[j][l] as 4 MFMAs
//   (A-frag = E, B-frag = S). S staged via global_load_lds (uniform row base +
//   lane*4 = the wave-uniform DMA pattern), rows padded to 65 dw for 2-way-free
//   banks. E staged via 2 global_load_lds size=16. Double-buffered as SEPARATE
//   __shared__ objects (so LDS-DMA alias analysis can tell them apart); manual
//   vmcnt(34/35) waits pipeline node p+1's 35 loads under node p's consume.
// G stored to g_lds in phase-B A-frag chunk order (chunk = (n>>3)*64 + l,
//   XOR (node&7) swizzle), bf16 RNE.
// Phase B: 32 K-steps, 1 ds_read_b128 A-frag + 4 MFMA (m-tiles), B = wt rows
//   (L2-resident). Output transposed through LDS -> 4 coalesced 1KB stores.
// LDS: 32768 (g_lds) + 2*8320 (S) + 2*2048 (E) = 53504 B -> 3 blocks/CU.
// ============================================================================
template <bool USE_WT>
__global__ __launch_bounds__(64, 1)
void mp_kernel(const float* __restrict__ nodes, const int* __restrict__ nlist,
               const float* __restrict__ edges, const unsigned short* __restrict__ wt,
               const float* __restrict__ w, float* __restrict__ out) {
  __shared__ u32 g_lds[8192];                 // 32 KB
  __shared__ u32 sbufA[2080], sbufB[2080];    // 32 rows x 65 dw each
  __shared__ u32 ebufA[512], ebufB[512];      // 32 rows x 16 f32 each

  const int lane = threadIdx.x;               // 0..63
  const int q = lane >> 4, c = lane & 15;

  // XCD-aware mapping: batch b's 4 MB nodes slab pinned to 4 XCDs' L2.
  const int blk = blockIdx.x;
  const int xcd = blk & 7;
  const int batch = xcd >> 2;
  const int ordinal = ((blk >> 3) << 2) + (xcd & 3);    // [0,1024)
  const int wg0 = (batch << LOGN) + (ordinal << 4);
  const float* __restrict__ nbase = nodes + ((size_t)batch << 20);

  auto load_nl = [&](int node) -> int {
    return nlist[(((size_t)(wg0 + node)) << 5) + (lane & 31)];
  };
  auto issue_S = [&](u32* sb, int nlv) {
    #pragma unroll
    for (int j = 0; j < 32; ++j) {
      const int ix = __builtin_amdgcn_readlane(nlv, j);   // wave-uniform
      const float* rp = nbase + (((size_t)(u32)ix) << 6);
      __builtin_amdgcn_global_load_lds((GlbU32*)(rp + lane), (LdsU32*)(sb + j * 65), 4, 0, 0);
    }
  };
  auto issue_E = [&](int node, u32* eb) {
    const char* ep = (const char*)(edges + (((size_t)(wg0 + node)) << 9));
    __builtin_amdgcn_global_load_lds((GlbU32*)(ep + lane * 16), (LdsU32*)eb, 16, 0, 0);
    __builtin_amdgcn_global_load_lds((GlbU32*)(ep + 1024 + lane * 16), (LdsU32*)(eb + 256), 16, 0, 0);
  };
  auto consume = [&](int node, const u32* sb, const u32* eb) {
    const float* ef = (const float*)eb;
    const float* sf = (const float*)sb;
    float e[8];
    #pragma unroll
    for (int i = 0; i < 8; ++i) e[i] = ef[(q * 8 + i) * 16 + c];   // E[j=q*8+i][n=c]
    uint4 apk{pkrne(e[0], e[1]), pkrne(e[2], e[3]), pkrne(e[4], e[5]), pkrne(e[6], e[7])};
    bf16x8 af = __builtin_bit_cast(bf16x8, apk);
    #pragma unroll
    for (int lt = 0; lt < 4; ++lt) {
      float s[8];
      #pragma unroll
      for (int i = 0; i < 8; ++i) s[i] = sf[(q * 8 + i) * 65 + lt * 16 + c]; // S[j][l=lt*16+c]
      uint4 spk{pkrne(s[0], s[1]), pkrne(s[2], s[3]), pkrne(s[4], s[5]), pkrne(s[6], s[7])};
      bf16x8 bf = __builtin_bit_cast(bf16x8, spk);
      f32x4 acc{0.f, 0.f, 0.f, 0.f};
      acc = __builtin_amdgcn_mfma_f32_16x16x32_bf16(af, bf, acc, 0, 0, 0);
      // lane holds G^T[n=q*4+r][l=lt*16+c]; chunk = (n>>3)*64 + l, pos (n&7)*2B
      u32 lo = pkrne(acc[0], acc[1]);
      u32 hi = pkrne(acc[2], acc[3]);
      const int chunk = (((q >> 1) << 6) + lt * 16 + c) ^ (node & 7);
      *(uint2*)&g_lds[node * 512 + chunk * 4 + (q & 1) * 2] = uint2{lo, hi};
    }
  };

  // ---------------- Phase A pipeline ----------------
  {
    int nlv0, nlv1;
    int nl_t = load_nl(0);
    nlv1 = load_nl(1);
    issue_S(sbufA, nl_t);      // compiler waits nl_t before readlanes (nlv1 stays in flight)
    issue_E(0, ebufA);
    // invariant at each step entry: outstanding = nlv(next)[1, oldest] + S(p)[32] + E(p)[2]
    #pragma unroll 1
    for (int pp = 0; pp < 16; pp += 2) {
      // p = pp (even): consume A, issue into B
      WAITVM(34);                                   // drains nlv for p+1
      {
        const int nlcur = nlv1;
        nlv0 = load_nl(pp + 2 < 16 ? pp + 2 : 15);  // nlv for p+2 (clamped)
        issue_S(sbufB, nlcur);
        issue_E(pp + 1 < 16 ? pp + 1 : 15, ebufB);
        WAITVM(35);                                 // drains S(p), E(p)
        consume(pp, sbufA, ebufA);
      }
      // p = pp+1 (odd): consume B, issue into A
      WAITVM(34);
      {
        const int nlcur = nlv0;
        nlv1 = load_nl(pp + 3 < 16 ? pp + 3 : 15);
        issue_S(sbufA, nlcur);
        issue_E(pp + 2 < 16 ? pp + 2 : 15, ebufA);
        WAITVM(35);
        consume(pp + 1, sbufB, ebufB);
      }
    }
  }

  // ---------------- Phase B: out = G @ wt^T ----------------
  const int cbase = ((q & 1) << 6) + (q >> 1);
  f32x4 ob[4] = {{0.f,0.f,0.f,0.f},{0.f,0.f,0.f,0.f},{0.f,0.f,0.f,0.f},{0.f,0.f,0.f,0.f}};
  if (USE_WT) {
    const unsigned short* wb = wt + (c << 10) + (q << 3);   // wt[m=c][k=q*8..]
    #pragma unroll 4
    for (int s = 0; s < 32; ++s) {
      uint4 ar = *(const uint4*)&g_lds[(c << 9) + (((cbase + 2 * s) ^ (c & 7)) << 2)];
      bf16x8 af = __builtin_bit_cast(bf16x8, ar);
      ob[0] = __builtin_amdgcn_mfma_f32_16x16x32_bf16(af, *(const bf16x8*)(wb + s * 32), ob[0], 0, 0, 0);
      ob[1] = __builtin_amdgcn_mfma_f32_16x16x32_bf16(af, *(const bf16x8*)(wb + 16384 + s * 32), ob[1], 0, 0, 0);
      ob[2] = __builtin_amdgcn_mfma_f32_16x16x32_bf16(af, *(const bf16x8*)(wb + 32768 + s * 32), ob[2], 0, 0, 0);
      ob[3] = __builtin_amdgcn_mfma_f32_16x16x32_bf16(af, *(const bf16x8*)(wb + 49152 + s * 32), ob[3], 0, 0, 0);
    }
  } else {
    #pragma unroll 2
    for (int s = 0; s < 32; ++s) {
      uint4 ar = *(const uint4*)&g_lds[(c << 9) + (((cbase + 2 * s) ^ (c & 7)) << 2)];
      bf16x8 af = __builtin_bit_cast(bf16x8, ar);
      const int l = 2 * s + (q >> 1);
      const float* wp = w + l * 1024 + c * 16 + (q & 1) * 8;
      #pragma unroll
      for (int mt = 0; mt < 4; ++mt)
        ob[mt] = __builtin_amdgcn_mfma_f32_16x16x32_bf16(af, mk_bw(wp + mt * 256), ob[mt], 0, 0, 0);
    }
  }

  // Output: transpose through LDS (reuse g_lds; same-wave, program order) ->
  // 4 fully-coalesced 1KB stores. Row stride 68 dw keeps 16B align + ok banks.
  u32* spad = g_lds;
  #pragma unroll
  for (int mt = 0; mt < 4; ++mt) {
    #pragma unroll
    for (int r = 0; r < 4; ++r)
      spad[(q * 4 + r) * 68 + mt * 16 + c] = fbits(ob[mt][r]);   // [node][m]
  }
  const int onode = lane >> 2, oseg = lane & 3;
  float* orow = out + ((size_t)(wg0 + onode) << 6) + oseg * 16;
  #pragma unroll
  for (int t = 0; t < 4; ++t)
    *(uint4*)(orow + t * 4) = *(const uint4*)&spad[onode * 68 + oseg * 16 + t * 4];
}

extern "C" void kernel_launch(void* const* d_in, const int* in_sizes, int n_in,
                              void* d_out, int out_size, void* d_ws, size_t ws_size,
                              hipStream_t stream) {
  const float* nodes = (const float*)d_in[0];
  const int*   nlist = (const int*)d_in[1];
  const float* edges = (const float*)d_in[2];
  const float* w     = (const float*)d_in[3];
  float* out = (float*)d_out;

  if (ws_size >= 131072) {
    unsigned short* wt = (unsigned short*)d_ws;
    prep_wt<<<256, 256, 0, stream>>>(w, wt);
    mp_kernel<true><<<2048, 64, 0, stream>>>(nodes, nlist, edges, wt, w, out);
  } else {
    mp_kernel<false><<<2048, 64, 0, stream>>>(nodes, nlist, edges, nullptr, w, out);
  }
}

// Round 6
// 149.795 us; speedup vs baseline: 1.3969x; 1.3469x over previous
//
#include <hip/hip_runtime.h>
#include <cstdint>
#include <cstddef>

// Problem constants: B=2, N=16384, K=32, F=64, E=16
#define LOGN 14

typedef __bf16 bf16x8 __attribute__((ext_vector_type(8)));
typedef float f32x4 __attribute__((ext_vector_type(4)));
typedef unsigned u32;

// raw barrier + lgkmcnt(0)-only wait (vmcnt/expcnt unconstrained: 0xC07F)
#define BARRIER() __builtin_amdgcn_s_barrier()
#define LGKM0()   __builtin_amdgcn_s_waitcnt(0xC07F)

__device__ __forceinline__ u32 fbits(float f) { return __builtin_bit_cast(u32, f); }
// pack two f32 -> dword of 2 bf16 (RNE), lo -> low16
__device__ __forceinline__ u32 pkrne(float lo, float hi) {
  u32 a = fbits(lo); a = a + 0x7fffu + ((a >> 16) & 1u);
  u32 b = fbits(hi); b = b + 0x7fffu + ((b >> 16) & 1u);
  return (b & 0xffff0000u) | (a >> 16);
}

// wt[m][k] = w[l][m][n]/32, k = l*16+n (bf16), 64x1024 = 128KB
__global__ void prep_wt(const float* __restrict__ w, unsigned short* __restrict__ wt) {
  int idx = blockIdx.x * 256 + threadIdx.x;
  int m = idx >> 10, k = idx & 1023, l = k >> 4, n = k & 15;
  u32 u = fbits(w[l * 1024 + m * 16 + n] * 0.03125f);
  wt[idx] = (unsigned short)((u + 0x7fffu + ((u >> 16) & 1u)) >> 16);
}

__device__ __forceinline__ bf16x8 mk_bw(const float* wp) {
  float v[8];
  #pragma unroll
  for (int i = 0; i < 8; ++i) v[i] = wp[i] * 0.03125f;
  uint4 pk{pkrne(v[0], v[1]), pkrne(v[2], v[3]), pkrne(v[4], v[5]), pkrne(v[6], v[7])};
  return __builtin_bit_cast(bf16x8, pk);
}

// ============================================================================
// WG = 256 threads (4 waves) = 16 nodes; all 4 waves cooperate on EACH node:
// phase A per node is G^T[n_e][l] = sum_j E[j][n_e]*S[j][l]; wave wid owns
// l-tile lt=wid (one 16x16x32 MFMA). S rows gathered 8/wave into VGPRs (saddr
// loads, indices via v_readlane from a once-per-kernel nlist vector load —
// no SMEM, no LDS-DMA), depth-2 prefetch; staged via plain ds_write (lgkmcnt,
// in-order). Raw s_barrier (NO vmcnt drain) x2 per node; gathers stay in
// flight across barriers.
// LDS: g_lds 32KB (G, bf16, k-chunk layout chunk=k>>3 ^ node&7) +
//      S 32x65 dw (2-way-free) + E 32x22 dw (2-way-free) = 43.9KB -> 3 blk/CU.
// Phase B: wave wid = m-tile; 32 K-steps x (ds_read_b128 A + 16B wt load + MFMA).
// ============================================================================
template <bool USE_WT>
__global__ __launch_bounds__(256, 3)
void mp_kernel(const float* __restrict__ nodes, const int* __restrict__ nlist,
               const float* __restrict__ edges, const unsigned short* __restrict__ wt,
               const float* __restrict__ w, float* __restrict__ out) {
  __shared__ u32 g_lds[16 * 512];   // 32 KB
  __shared__ u32 sbuf[32 * 65];     // 8320 B: S[j][l], pad 65
  __shared__ u32 ebuf[32 * 22];     // 2816 B: E[j][n], pad 22

  const int tid = threadIdx.x;
  const int lane = tid & 63;
  const int wid = __builtin_amdgcn_readfirstlane(tid >> 6);
  const int q = lane >> 4, c = lane & 15;

  // XCD-aware mapping: batch b's 4 MB nodes slab pinned to 4 XCDs' L2.
  const int blk = blockIdx.x;
  const int xcd = blk & 7;
  const int batch = xcd >> 2;
  const int ordinal = ((blk >> 3) << 2) + (xcd & 3);    // [0,1024)
  const int wg0 = (batch << LOGN) + (ordinal << 4);
  const float* __restrict__ nbase = nodes + ((size_t)batch << 20);

  // nlist for this wave's rows (j = wid*8..wid*8+7) of all 16 nodes:
  // 128 ints, one int2 per lane. Element (p,i) at lane 4p+(i>>1), comp i&1.
  const int* __restrict__ nlp = nlist + (((size_t)wg0) << 5) + (wid << 3);
  const int2 nlv = *(const int2*)(nlp + ((lane >> 2) << 5) + ((lane & 3) << 1));

  float gv[2][8];     // gathered S rows, depth-2 pipeline
  float2 ge[2];       // this wave's E quarter

  const float* __restrict__ ebase = edges + (((size_t)wg0) << 9) + (wid << 7);

  #define ISSUE(p, slot)                                                        \
    {                                                                           \
      _Pragma("unroll")                                                         \
      for (int i = 0; i < 8; ++i) {                                             \
        const int ix = __builtin_amdgcn_readlane((i & 1) ? nlv.y : nlv.x,       \
                                                 4 * (p) + (i >> 1));           \
        gv[slot][i] = nbase[(((size_t)(u32)ix) << 6) + lane];                   \
      }                                                                         \
      ge[slot] = *(const float2*)(ebase + ((p) << 9) + (lane << 1));            \
    }

  ISSUE(0, 0)
  ISSUE(1, 1)

  const int erow = (wid << 3) + (lane >> 3);
  const int ecol = (lane & 7) << 1;

  #pragma unroll
  for (int p = 0; p < 16; ++p) {
    const int slot = p & 1;
    BARRIER();                       // prior reads of sbuf/ebuf finished
    // stage S rows + E quarter (plain ds_write; vmcnt waits for gv are precise)
    #pragma unroll
    for (int i = 0; i < 8; ++i)
      sbuf[((wid << 3) + i) * 65 + lane] = fbits(gv[slot][i]);
    *(uint2*)&ebuf[erow * 22 + ecol] = uint2{fbits(ge[slot].x), fbits(ge[slot].y)};
    if (p < 14) ISSUE(p + 2, slot)   // refill after the reads of gv[slot]
    LGKM0();                         // S/E writes visible
    BARRIER();
    // ---- consume node p: one MFMA, l-tile = wid ----
    {
      const float* ef = (const float*)ebuf;
      const float* sf = (const float*)sbuf;
      float e[8];
      #pragma unroll
      for (int i = 0; i < 8; ++i) e[i] = ef[(q * 8 + i) * 22 + c];      // E[j][n=c]
      uint4 apk{pkrne(e[0], e[1]), pkrne(e[2], e[3]), pkrne(e[4], e[5]), pkrne(e[6], e[7])};
      float s[8];
      #pragma unroll
      for (int i = 0; i < 8; ++i) s[i] = sf[(q * 8 + i) * 65 + (wid << 4) + c]; // S[j][l]
      uint4 spk{pkrne(s[0], s[1]), pkrne(s[2], s[3]), pkrne(s[4], s[5]), pkrne(s[6], s[7])};
      f32x4 acc{0.f, 0.f, 0.f, 0.f};
      acc = __builtin_amdgcn_mfma_f32_16x16x32_bf16(__builtin_bit_cast(bf16x8, apk),
                                                    __builtin_bit_cast(bf16x8, spk),
                                                    acc, 0, 0, 0);
      // lane holds G^T[n=4q+r][L=wid*16+c]; k=16L+n; chunk=k>>3 = 2L+(q>>1),
      // pos n&7 = 4(q&1)+r -> uint2 at dw offset chunk*4 + 2(q&1), ^ (p&7).
      const u32 lo = pkrne(acc[0], acc[1]);
      const u32 hi = pkrne(acc[2], acc[3]);
      const int chunk = (((wid << 4) + c) * 2 + (q >> 1)) ^ (p & 7);
      *(uint2*)&g_lds[(p << 9) + (chunk << 2) + ((q & 1) << 1)] = uint2{lo, hi};
    }
  }
  #undef ISSUE

  LGKM0();
  BARRIER();

  // ---------------- Phase B: out[node][m] = sum_k G2[node][k] * wt[m][k] ----
  // A-frag: lane(q,c): G2[node=c][k=32s+8q+i] -> chunk 4s+q (^c&7), b128.
  const int m = (wid << 4) + c;
  f32x4 ob{0.f, 0.f, 0.f, 0.f};
  if (USE_WT) {
    const unsigned short* wb = wt + ((size_t)m << 10) + (q << 3);
    #pragma unroll 8
    for (int s = 0; s < 32; ++s) {
      uint4 ar = *(const uint4*)&g_lds[(c << 9) + ((((s << 2) + q) ^ (c & 7)) << 2)];
      ob = __builtin_amdgcn_mfma_f32_16x16x32_bf16(__builtin_bit_cast(bf16x8, ar),
                                                   *(const bf16x8*)(wb + (s << 5)),
                                                   ob, 0, 0, 0);
    }
  } else {
    #pragma unroll 4
    for (int s = 0; s < 32; ++s) {
      uint4 ar = *(const uint4*)&g_lds[(c << 9) + ((((s << 2) + q) ^ (c & 7)) << 2)];
      const int l = 2 * s + (q >> 1);
      const float* wp = w + l * 1024 + m * 16 + ((q & 1) << 3);
      ob = __builtin_amdgcn_mfma_f32_16x16x32_bf16(__builtin_bit_cast(bf16x8, ar),
                                                   mk_bw(wp), ob, 0, 0, 0);
    }
  }

  // D: lane(q,c): out[node = 4q+r][mfeat = m]
  #pragma unroll
  for (int r = 0; r < 4; ++r)
    out[((size_t)(wg0 + (q << 2) + r) << 6) + m] = ob[r];
}

extern "C" void kernel_launch(void* const* d_in, const int* in_sizes, int n_in,
                              void* d_out, int out_size, void* d_ws, size_t ws_size,
                              hipStream_t stream) {
  const float* nodes = (const float*)d_in[0];
  const int*   nlist = (const int*)d_in[1];
  const float* edges = (const float*)d_in[2];
  const float* w     = (const float*)d_in[3];
  float* out = (float*)d_out;

  if (ws_size >= 131072) {
    unsigned short* wt = (unsigned short*)d_ws;
    prep_wt<<<256, 256, 0, stream>>>(w, wt);
    mp_kernel<true><<<2048, 256, 0, stream>>>(nodes, nlist, edges, wt, w, out);
  } else {
    mp_kernel<false><<<2048, 256, 0, stream>>>(nodes, nlist, edges, nullptr, w, out);
  }
}

// Round 7
// 148.055 us; speedup vs baseline: 1.4133x; 1.0118x over previous
//
#include <hip/hip_runtime.h>
#include <cstdint>
#include <cstddef>

// Problem constants: B=2, N=16384, K=32, F=64, E=16
#define LOGN 14

typedef __bf16 bf16x8 __attribute__((ext_vector_type(8)));
typedef float f32x4 __attribute__((ext_vector_type(4)));
typedef unsigned u32;

// raw barrier + lgkmcnt(0)-only wait (vmcnt/expcnt unconstrained: 0xC07F)
#define BARRIER() __builtin_amdgcn_s_barrier()
#define LGKM0()   __builtin_amdgcn_s_waitcnt(0xC07F)

__device__ __forceinline__ u32 fbits(float f) { return __builtin_bit_cast(u32, f); }
// pack two f32 -> dword of 2 bf16 (RNE), lo -> low16
__device__ __forceinline__ u32 pkrne(float lo, float hi) {
  u32 a = fbits(lo); a = a + 0x7fffu + ((a >> 16) & 1u);
  u32 b = fbits(hi); b = b + 0x7fffu + ((b >> 16) & 1u);
  return (b & 0xffff0000u) | (a >> 16);
}

// wt[m][k] = w[l][m][n]/32, k = l*16+n (bf16), 64x1024 = 128KB
__global__ void prep_wt(const float* __restrict__ w, unsigned short* __restrict__ wt) {
  int idx = blockIdx.x * 256 + threadIdx.x;
  int m = idx >> 10, k = idx & 1023, l = k >> 4, n = k & 15;
  u32 u = fbits(w[l * 1024 + m * 16 + n] * 0.03125f);
  wt[idx] = (unsigned short)((u + 0x7fffu + ((u >> 16) & 1u)) >> 16);
}

__device__ __forceinline__ bf16x8 mk_bw(const float* wp) {
  float v[8];
  #pragma unroll
  for (int i = 0; i < 8; ++i) v[i] = wp[i] * 0.03125f;
  uint4 pk{pkrne(v[0], v[1]), pkrne(v[2], v[3]), pkrne(v[4], v[5]), pkrne(v[6], v[7])};
  return __builtin_bit_cast(bf16x8, pk);
}

// ============================================================================
// WG = 256 threads (4 waves) = 16 nodes; wave wid owns nodes wid*4..wid*4+3
// end-to-end in phase A — NO barriers, NO S/E LDS staging (R6's DS-pipe bind).
// Per node: MFMA fragments gathered DIRECTLY from global in frag layout:
//   A-frag lane(q,c) reg i = E[j=q*8+i][n=c]      (coalesced 256B/instr)
//   B-frag lane(q,c) reg i = S[j=q*8+i][L=lt*16+c] (4 l-tiles share one row
//     base -> 4 dword loads w/ imm offsets, one 64b addr calc per row)
//   Row indices: per-lane int4 pair from nlist (quadrant-broadcast loads).
// Depth-2 software pipeline: nl 2 nodes ahead, S/E 1 node ahead; all waits are
// precise vmcnt on plain loads. 4 MFMAs/node -> G (bf16, RNE) -> 4 ds_write_b64
// into g_lds (k-chunk layout, chunk = 2L+(q>>1) ^ node&7). LDS = 32 KB only.
// Phase B (unchanged from R6): wave wid = m-tile; 32 K-steps x
// (ds_read_b128 A + 16B wt load + MFMA); wt is L2-resident.
// ============================================================================
template <bool USE_WT>
__global__ __launch_bounds__(256, 3)
void mp_kernel(const float* __restrict__ nodes, const int* __restrict__ nlist,
               const float* __restrict__ edges, const unsigned short* __restrict__ wt,
               const float* __restrict__ w, float* __restrict__ out) {
  __shared__ u32 g_lds[16 * 512];   // 32 KB: G (bf16) in phase-B A-frag order

  const int tid = threadIdx.x;
  const int lane = tid & 63;
  const int wid = __builtin_amdgcn_readfirstlane(tid >> 6);
  const int q = lane >> 4, c = lane & 15;

  // XCD-aware mapping: batch b's 4 MB nodes slab pinned to 4 XCDs' L2.
  const int blk = blockIdx.x;
  const int xcd = blk & 7;
  const int batch = xcd >> 2;
  const int ordinal = ((blk >> 3) << 2) + (xcd & 3);    // [0,1024)
  const int wg0 = (batch << LOGN) + (ordinal << 4);
  const float* __restrict__ nbase = nodes + ((size_t)batch << 20);

  const int nd0 = wid << 2;                              // this wave's first node

  auto issue_nl = [&](int t, int4* ni) {
    const int* r = nlist + (((size_t)(wg0 + nd0 + t)) << 5) + (q << 3);
    ni[0] = *(const int4*)r;        // ix[q*8+0 .. +3]
    ni[1] = *(const int4*)(r + 4);  // ix[q*8+4 .. +7]
  };
  auto issue_se = [&](int t, const int4* ni, float* S, float* E) {
    const int ix[8] = {ni[0].x, ni[0].y, ni[0].z, ni[0].w,
                       ni[1].x, ni[1].y, ni[1].z, ni[1].w};
    #pragma unroll
    for (int i = 0; i < 8; ++i) {
      const float* rp = nbase + ((size_t)(u32)ix[i] << 6) + c;
      #pragma unroll
      for (int lt = 0; lt < 4; ++lt) S[i * 4 + lt] = rp[lt << 4];
    }
    const float* ep = edges + (((size_t)(wg0 + nd0 + t)) << 9) + (q << 7) + c;
    #pragma unroll
    for (int i = 0; i < 8; ++i) E[i] = ep[i << 4];
  };
  auto consume = [&](int p, const float* S, const float* E) {
    uint4 apk{pkrne(E[0], E[1]), pkrne(E[2], E[3]),
              pkrne(E[4], E[5]), pkrne(E[6], E[7])};
    const bf16x8 af = __builtin_bit_cast(bf16x8, apk);
    #pragma unroll
    for (int lt = 0; lt < 4; ++lt) {
      uint4 spk{pkrne(S[0 * 4 + lt], S[1 * 4 + lt]),
                pkrne(S[2 * 4 + lt], S[3 * 4 + lt]),
                pkrne(S[4 * 4 + lt], S[5 * 4 + lt]),
                pkrne(S[6 * 4 + lt], S[7 * 4 + lt])};
      f32x4 acc{0.f, 0.f, 0.f, 0.f};
      acc = __builtin_amdgcn_mfma_f32_16x16x32_bf16(af,
              __builtin_bit_cast(bf16x8, spk), acc, 0, 0, 0);
      // lane holds G^T[n=4q+r][L=lt*16+c]; chunk = (2L+(q>>1)) ^ (p&7)
      const u32 lo = pkrne(acc[0], acc[1]);
      const u32 hi = pkrne(acc[2], acc[3]);
      const int chunk = ((((lt << 4) + c) << 1) + (q >> 1)) ^ (p & 7);
      *(uint2*)&g_lds[(p << 9) + (chunk << 2) + ((q & 1) << 1)] = uint2{lo, hi};
    }
  };

  // ---------------- Phase A: barrier-free depth-2 pipeline ----------------
  {
    int4 ni0[2], ni1[2];
    float S0[32], E0[8], S1[32], E1[8];
    issue_nl(0, ni0);
    issue_nl(1, ni1);
    issue_se(0, ni0, S0, E0);       // waits nl(0) only; nl(1) stays in flight
    issue_nl(2, ni0);
    issue_se(1, ni1, S1, E1);       // waits nl(1); SE(0)+nl(2) in flight
    issue_nl(3, ni1);
    consume(nd0 + 0, S0, E0);       // waits SE(0); SE(1)+nl(3) in flight
    issue_se(2, ni0, S0, E0);
    consume(nd0 + 1, S1, E1);
    issue_se(3, ni1, S1, E1);
    consume(nd0 + 2, S0, E0);
    consume(nd0 + 3, S1, E1);
  }

  LGKM0();      // G writes visible
  BARRIER();

  // ---------------- Phase B: out[node][m] = sum_k G2[node][k] * wt[m][k] ----
  // A-frag: lane(q,c): G2[node=c][k=32s+8q+i] -> chunk 4s+q (^c&7), b128.
  const int m = (wid << 4) + c;
  f32x4 ob{0.f, 0.f, 0.f, 0.f};
  if (USE_WT) {
    const unsigned short* wb = wt + ((size_t)m << 10) + (q << 3);
    #pragma unroll 8
    for (int s = 0; s < 32; ++s) {
      uint4 ar = *(const uint4*)&g_lds[(c << 9) + ((((s << 2) + q) ^ (c & 7)) << 2)];
      ob = __builtin_amdgcn_mfma_f32_16x16x32_bf16(__builtin_bit_cast(bf16x8, ar),
                                                   *(const bf16x8*)(wb + (s << 5)),
                                                   ob, 0, 0, 0);
    }
  } else {
    #pragma unroll 4
    for (int s = 0; s < 32; ++s) {
      uint4 ar = *(const uint4*)&g_lds[(c << 9) + ((((s << 2) + q) ^ (c & 7)) << 2)];
      const int l = 2 * s + (q >> 1);
      const float* wp = w + l * 1024 + m * 16 + ((q & 1) << 3);
      ob = __builtin_amdgcn_mfma_f32_16x16x32_bf16(__builtin_bit_cast(bf16x8, ar),
                                                   mk_bw(wp), ob, 0, 0, 0);
    }
  }

  // D: lane(q,c): out[node = 4q+r][mfeat = m]
  #pragma unroll
  for (int r = 0; r < 4; ++r)
    out[((size_t)(wg0 + (q << 2) + r) << 6) + m] = ob[r];
}

extern "C" void kernel_launch(void* const* d_in, const int* in_sizes, int n_in,
                              void* d_out, int out_size, void* d_ws, size_t ws_size,
                              hipStream_t stream) {
  const float* nodes = (const float*)d_in[0];
  const int*   nlist = (const int*)d_in[1];
  const float* edges = (const float*)d_in[2];
  const float* w     = (const float*)d_in[3];
  float* out = (float*)d_out;

  if (ws_size >= 131072) {
    unsigned short* wt = (unsigned short*)d_ws;
    prep_wt<<<256, 256, 0, stream>>>(w, wt);
    mp_kernel<true><<<2048, 256, 0, stream>>>(nodes, nlist, edges, wt, w, out);
  } else {
    mp_kernel<false><<<2048, 256, 0, stream>>>(nodes, nlist, edges, nullptr, w, out);
  }
}